// Round 1
// baseline (2226.385 us; speedup 1.0000x reference)
//
#include <hip/hip_runtime.h>
#include <math.h>

#define BB 8
#define NN 4096
#define CC 256
#define DD 64
#define MM 1024
#define KNB 16
#define OC 259

// ---------------------------------------------------------------------------
// Transpose feature_map (B,C,N) -> (B,N,C) for coalesced per-point gathers.
__global__ __launch_bounds__(256) void transpose_fm(const float* __restrict__ fm,
                                                    float* __restrict__ fm_t) {
  __shared__ float tile[64][65];
  int b = blockIdx.z;
  int n0 = blockIdx.x * 64;
  int c0 = blockIdx.y * 64;
  const float* src = fm + (size_t)b * CC * NN;
  float* dst = fm_t + (size_t)b * NN * CC;
  int tx = threadIdx.x, ty = threadIdx.y;
  for (int r = ty; r < 64; r += 4)
    tile[r][tx] = src[(size_t)(c0 + r) * NN + n0 + tx];
  __syncthreads();
  for (int r = ty; r < 64; r += 4)
    dst[(size_t)(n0 + r) * CC + c0 + tx] = tile[tx][r];
}

// ---------------------------------------------------------------------------
// Fold BN into conv weights; transpose weights for coalesced access.
__global__ void prep_weights(
    const float* __restrict__ pw1, const float* __restrict__ pb1,
    const float* __restrict__ g1, const float* __restrict__ bb1,
    const float* __restrict__ m1, const float* __restrict__ v1,
    const float* __restrict__ pw2,
    const float* __restrict__ aw1, const float* __restrict__ ab1,
    const float* __restrict__ g2, const float* __restrict__ bb2,
    const float* __restrict__ m2, const float* __restrict__ v2,
    const float* __restrict__ aw2,
    float* __restrict__ w1f, float* __restrict__ b1f, float* __restrict__ ab1f,
    float* __restrict__ pw2t, float* __restrict__ aw1t, float* __restrict__ aw2t) {
  int tid = threadIdx.x;
  if (tid < 64) {
    float s = g1[tid] * rsqrtf(v1[tid] + 1e-5f);
    w1f[tid * 4 + 0] = pw1[tid * 3 + 0] * s;
    w1f[tid * 4 + 1] = pw1[tid * 3 + 1] * s;
    w1f[tid * 4 + 2] = pw1[tid * 3 + 2] * s;
    w1f[tid * 4 + 3] = 0.f;
    b1f[tid] = (pb1[tid] - m1[tid]) * s + bb1[tid];
    float s2 = g2[tid] * rsqrtf(v2[tid] + 1e-5f);
    ab1f[tid] = (ab1[tid] - m2[tid]) * s2 + bb2[tid];
  }
  // pw2t[i][c] = pw2[c][i]   (64 x 256)
  for (int x = tid; x < 64 * 256; x += 256) {
    int i = x >> 8, c = x & 255;
    pw2t[x] = pw2[c * 64 + i];
  }
  // aw1t[c][d] = aw1[d][c] * s2[d]   (256 x 64), bn2 folded
  for (int x = tid; x < 256 * 64; x += 256) {
    int c = x >> 6, d = x & 63;
    float s2 = g2[d] * rsqrtf(v2[d] + 1e-5f);
    aw1t[x] = aw1[d * 256 + c] * s2;
  }
  // aw2t[i][o] = aw2[o][i]   (64 x 260 padded)
  for (int x = tid; x < 64 * OC; x += 256) {
    int i = x / OC, o = x % OC;
    aw2t[i * 260 + o] = aw2[o * 64 + i];
  }
}

// ---------------------------------------------------------------------------
// Farthest point sampling: 1 block per batch, 1024 threads, 4 points/thread.
// Single barrier per step via monotone step-stamped u64 atomicMax slot.
__global__ __launch_bounds__(1024) void fps_kernel(const float* __restrict__ verts,
                                                   int* __restrict__ fps_idx) {
  int b = blockIdx.x;
  int tid = threadIdx.x;
  __shared__ float lx[NN], ly[NN], lz[NN];
  __shared__ unsigned long long slot;
  const float* vb = verts + (size_t)b * 3 * NN;
  float px[4], py[4], pz[4], dist[4];
#pragma unroll
  for (int r = 0; r < 4; ++r) {
    int j = tid + r * 1024;
    px[r] = vb[j];
    py[r] = vb[NN + j];
    pz[r] = vb[2 * NN + j];
    lx[j] = px[r];
    ly[j] = py[r];
    lz[j] = pz[r];
    dist[r] = 1e10f;
  }
  if (tid == 0) slot = 4095ull;  // stamp 0, dist 0, idx 0 (invidx=4095)
  __syncthreads();

  for (int s = 0; s < MM; ++s) {
    unsigned long long w = slot;
    int far = 4095 - (int)(w & 0xFFFull);
    if (tid == 0) fps_idx[b * MM + s] = far;
    if (s == MM - 1) break;
    float cx = lx[far], cy = ly[far], cz = lz[far];
    float bestv = -1.0f;
    int bestj = 0;
#pragma unroll
    for (int r = 0; r < 4; ++r) {
      float dx = px[r] - cx, dy = py[r] - cy, dz = pz[r] - cz;
      float d = dx * dx + dy * dy + dz * dz;
      dist[r] = fminf(dist[r], d);
      if (dist[r] > bestv) { bestv = dist[r]; bestj = tid + r * 1024; }
    }
    unsigned long long key =
        ((unsigned long long)__float_as_uint(bestv) << 12) |
        (unsigned long long)(4095 - bestj);
#pragma unroll
    for (int off = 32; off >= 1; off >>= 1) {
      unsigned long long o = __shfl_down(key, off, 64);
      key = (o > key) ? o : key;
    }
    if ((tid & 63) == 0) {
      unsigned long long full = ((unsigned long long)(s + 1) << 44) | key;
      atomicMax(&slot, full);
    }
    __syncthreads();
  }
}

// ---------------------------------------------------------------------------
// KNN top-16: one wave per key point. Dist buffer in LDS (64x65 padded),
// per-lane cached top-2 with lazy rescan, 16 wave-argmin rounds.
__global__ __launch_bounds__(64) void knn_kernel(const float* __restrict__ verts,
                                                 const int* __restrict__ fps_idx,
                                                 int* __restrict__ knn_idx) {
  int blk = blockIdx.x;
  int b = blk >> 10;
  int m = blk & 1023;
  int lane = threadIdx.x;
  __shared__ float dbuf[64 * 65];
  const float* vb = verts + (size_t)b * 3 * NN;
  int jm = fps_idx[b * MM + m];
  float kx = vb[jm], ky = vb[NN + jm], kz = vb[2 * NN + jm];
  float kn = kx * kx + ky * ky + kz * kz;
  float v1 = INFINITY, v2 = INFINITY;
  int i1 = -1, i2 = -1;
  for (int t = 0; t < 64; ++t) {
    int j = t * 64 + lane;
    float x = vb[j], y = vb[NN + j], z = vb[2 * NN + j];
    float xn = x * x + y * y + z * z;
    float d = kn + xn - 2.0f * (kx * x + ky * y + kz * z);
    dbuf[lane * 65 + t] = d;
    if (d < v1) { v2 = v1; i2 = i1; v1 = d; i1 = j; }
    else if (d < v2) { v2 = d; i2 = j; }
  }
  for (int it = 0; it < KNB; ++it) {
    float rv = v1;
    int ri = i1;
#pragma unroll
    for (int off = 32; off >= 1; off >>= 1) {
      float ov = __shfl_down(rv, off, 64);
      int oi = __shfl_down(ri, off, 64);
      if (ov < rv || (ov == rv && oi < ri)) { rv = ov; ri = oi; }
    }
    ri = __shfl(ri, 0, 64);
    if (lane == 0) knn_idx[(size_t)(b * MM + m) * KNB + it] = ri;
    if (i1 == ri) {
      dbuf[lane * 65 + (ri >> 6)] = INFINITY;
      v1 = v2; i1 = i2;
      v2 = INFINITY; i2 = -1;
      if (i1 < 0) {  // rescan my 64 slots
        v1 = INFINITY; v2 = INFINITY; i1 = -1; i2 = -1;
        for (int t = 0; t < 64; ++t) {
          float d = dbuf[lane * 65 + t];
          int j = t * 64 + lane;
          if (d < v1) { v2 = v1; i2 = i1; v1 = d; i1 = j; }
          else if (d < v2) { v2 = d; i2 = j; }
        }
      }
    }
  }
}

// ---------------------------------------------------------------------------
// Fused: conv1+bn1+lrelu -> conv2 (pos_embedding) -> conv3+bn2+lrelu ->
// conv4 -> softmax(k) -> weighted aggregation. One block per (b,m).
__global__ __launch_bounds__(256) void fused_kernel(
    const float* __restrict__ verts, const float* __restrict__ fm_t,
    const int* __restrict__ fps_idx, const int* __restrict__ knn_idx,
    const float* __restrict__ w1f, const float* __restrict__ b1f,
    const float* __restrict__ pw2t, const float* __restrict__ pb2,
    const float* __restrict__ aw1t, const float* __restrict__ ab1f,
    const float* __restrict__ aw2t, const float* __restrict__ ab2,
    float* __restrict__ out) {
  int b = blockIdx.x & 7;   // batch pinned to XCD (round-robin dispatch)
  int m = blockIdx.x >> 3;
  int tid = threadIdx.x;

  __shared__ float kf[CC];
  __shared__ float gp[3][KNB];
  __shared__ float kp[3];
  __shared__ int kidx[KNB];
  __shared__ float h_l[KNB][68];
  __shared__ float h2_l[KNB][68];
  __shared__ float t_l[KNB][260];
  __shared__ float wsm[KNB][260];

  const float* vb = verts + (size_t)b * 3 * NN;
  const float* fb = fm_t + (size_t)b * NN * CC;
  int jm = fps_idx[b * MM + m];
  if (tid < KNB) kidx[tid] = knn_idx[(size_t)(b * MM + m) * KNB + tid];
  if (tid < 3) kp[tid] = vb[tid * NN + jm];
  kf[tid] = fb[(size_t)jm * CC + tid];
  __syncthreads();
  if (tid < 48) {
    int c = tid >> 4, k = tid & 15;
    gp[c][k] = vb[c * NN + kidx[k]];
  }
  __syncthreads();

  // ---- Stage A: h[d][k] = lrelu(w1f . pos_rel + b1f)
  {
    int d = tid & 63, kq = tid >> 6;
    float wd0 = w1f[d * 4 + 0], wd1 = w1f[d * 4 + 1], wd2 = w1f[d * 4 + 2];
    float bd = b1f[d];
#pragma unroll
    for (int j = 0; j < 4; ++j) {
      int k = kq * 4 + j;
      float p0 = kp[0] - gp[0][k];
      float p1 = kp[1] - gp[1][k];
      float p2 = kp[2] - gp[2][k];
      float hv = wd0 * p0 + wd1 * p1 + wd2 * p2 + bd;
      h_l[k][d] = (hv > 0.f) ? hv : 0.2f * hv;
    }
  }
  __syncthreads();

  // ---- Stage B: pe = pw2 . h + pb2 ; t = (kf - gf) + pe  -> t_l
  {
    const int k = tid >> 4, cb = tid & 15;
    float acc[16];
#pragma unroll
    for (int j = 0; j < 16; ++j) acc[j] = 0.f;
    for (int i4 = 0; i4 < 64; i4 += 4) {
      float4 hv4 = *(const float4*)&h_l[k][i4];
      float hvv[4] = {hv4.x, hv4.y, hv4.z, hv4.w};
#pragma unroll
      for (int ii = 0; ii < 4; ++ii) {
        const float* wb = pw2t + (i4 + ii) * CC + cb * 16;
        float wv[16];
        *(float4*)&wv[0] = *(const float4*)(wb);
        *(float4*)&wv[4] = *(const float4*)(wb + 4);
        *(float4*)&wv[8] = *(const float4*)(wb + 8);
        *(float4*)&wv[12] = *(const float4*)(wb + 12);
        float h1 = hvv[ii];
#pragma unroll
        for (int j = 0; j < 16; ++j) acc[j] += wv[j] * h1;
      }
    }
    const float* gfp = fb + (size_t)kidx[k] * CC + cb * 16;
    float4 gf4[4], kf4[4], pb4[4];
#pragma unroll
    for (int q = 0; q < 4; ++q) {
      gf4[q] = *(const float4*)(gfp + 4 * q);
      kf4[q] = *(const float4*)(&kf[cb * 16 + 4 * q]);
      pb4[q] = *(const float4*)(pb2 + cb * 16 + 4 * q);
    }
    float tvv[16];
#pragma unroll
    for (int q = 0; q < 4; ++q) {
      const float* g = (const float*)&gf4[q];
      const float* kk = (const float*)&kf4[q];
      const float* pb = (const float*)&pb4[q];
#pragma unroll
      for (int r = 0; r < 4; ++r)
        tvv[4 * q + r] = kk[r] - g[r] + (acc[4 * q + r] + pb[r]);
    }
#pragma unroll
    for (int q = 0; q < 4; ++q)
      *(float4*)&t_l[k][cb * 16 + 4 * q] = *(float4*)&tvv[4 * q];
  }
  __syncthreads();

  // ---- Stage C: h2 = lrelu(aw1f . t + ab1f)
  {
    const int k = tid & 15, d2 = tid >> 4;
    float acc[4] = {0.f, 0.f, 0.f, 0.f};
    for (int c4 = 0; c4 < CC; c4 += 4) {
      float4 tv = *(const float4*)&t_l[k][c4];
      float tw[4] = {tv.x, tv.y, tv.z, tv.w};
#pragma unroll
      for (int cc = 0; cc < 4; ++cc) {
        float4 w = *(const float4*)(aw1t + (c4 + cc) * DD + d2 * 4);
        acc[0] += tw[cc] * w.x;
        acc[1] += tw[cc] * w.y;
        acc[2] += tw[cc] * w.z;
        acc[3] += tw[cc] * w.w;
      }
    }
    float hvv[4];
#pragma unroll
    for (int j = 0; j < 4; ++j) {
      float hv = acc[j] + ab1f[d2 * 4 + j];
      hvv[j] = (hv > 0.f) ? hv : 0.2f * hv;
    }
    *(float4*)&h2_l[k][d2 * 4] = *(float4*)&hvv[0];
  }
  __syncthreads();

  // ---- Stage D: logits = aw2 . h2 + ab2 ; softmax over k -> wsm
  {
    const int k = tid & 15, o2 = tid >> 4;
    float acc[16], accx = 0.f;
#pragma unroll
    for (int j = 0; j < 16; ++j) acc[j] = 0.f;
    const int oxcol = 256 + (o2 < 3 ? o2 : 0);
    for (int i4 = 0; i4 < 64; i4 += 4) {
      float4 hv4 = *(const float4*)&h2_l[k][i4];
      float hvv[4] = {hv4.x, hv4.y, hv4.z, hv4.w};
#pragma unroll
      for (int ii = 0; ii < 4; ++ii) {
        const float* wb = aw2t + (i4 + ii) * 260 + o2 * 16;
        float wv[16];
        *(float4*)&wv[0] = *(const float4*)(wb);
        *(float4*)&wv[4] = *(const float4*)(wb + 4);
        *(float4*)&wv[8] = *(const float4*)(wb + 8);
        *(float4*)&wv[12] = *(const float4*)(wb + 12);
        float h1 = hvv[ii];
#pragma unroll
        for (int j = 0; j < 16; ++j) acc[j] += wv[j] * h1;
        accx += aw2t[(i4 + ii) * 260 + oxcol] * h1;
      }
    }
#pragma unroll
    for (int j = 0; j < 17; ++j) {
      if (j == 16 && o2 >= 3) break;
      int o = (j < 16) ? (o2 * 16 + j) : (256 + o2);
      float lg = ((j < 16) ? acc[j] : accx) + ab2[o];
      float mx = lg;
#pragma unroll
      for (int msk = 8; msk >= 1; msk >>= 1)
        mx = fmaxf(mx, __shfl_xor(mx, msk, 64));
      float e = __expf(lg - mx);
      float sm = e;
#pragma unroll
      for (int msk = 8; msk >= 1; msk >>= 1) sm += __shfl_xor(sm, msk, 64);
      wsm[k][o] = e / sm;
    }
  }
  __syncthreads();

  // ---- Final: weighted aggregation.  gf+pe == t - kf + 2*gf
  {
    int c = tid;
    float kfc = kf[c];
    float acc = 0.f;
#pragma unroll
    for (int k = 0; k < KNB; ++k) {
      float wv = wsm[k][3 + c];
      float gfv = fb[(size_t)kidx[k] * CC + c];
      float tv = t_l[k][c];
      acc += wv * (tv - kfc + 2.0f * gfv);
    }
    out[((size_t)b * OC + (3 + c)) * MM + m] = acc;
    if (tid < 3) {
      float a2 = 0.f;
#pragma unroll
      for (int k = 0; k < KNB; ++k) a2 += wsm[k][tid] * gp[tid][k];
      out[((size_t)b * OC + tid) * MM + m] = a2;
    }
  }
}

// ---------------------------------------------------------------------------
extern "C" void kernel_launch(void* const* d_in, const int* in_sizes, int n_in,
                              void* d_out, int out_size, void* d_ws, size_t ws_size,
                              hipStream_t stream) {
  (void)in_sizes; (void)n_in; (void)out_size; (void)ws_size;
  const float* verts = (const float*)d_in[0];
  const float* fm = (const float*)d_in[1];
  const float* pw1 = (const float*)d_in[2];
  const float* pb1 = (const float*)d_in[3];
  const float* g1 = (const float*)d_in[4];
  const float* bb1 = (const float*)d_in[5];
  const float* m1 = (const float*)d_in[6];
  const float* v1 = (const float*)d_in[7];
  const float* pw2 = (const float*)d_in[8];
  const float* pb2 = (const float*)d_in[9];
  const float* aw1 = (const float*)d_in[10];
  const float* ab1 = (const float*)d_in[11];
  const float* g2 = (const float*)d_in[12];
  const float* bb2 = (const float*)d_in[13];
  const float* m2 = (const float*)d_in[14];
  const float* v2 = (const float*)d_in[15];
  const float* aw2 = (const float*)d_in[16];
  const float* ab2 = (const float*)d_in[17];
  float* out = (float*)d_out;

  char* ws = (char*)d_ws;
  float* fm_t = (float*)ws;                              // 33,554,432 B
  int* fpsi = (int*)(ws + 33554432);                     // 32,768 B
  int* knni = (int*)(ws + 33554432 + 32768);             // 524,288 B
  float* w1f = (float*)(ws + 34111488);
  float* b1f = w1f + 256;
  float* ab1f = b1f + 64;
  float* pw2t = ab1f + 64;
  float* aw1t = pw2t + 64 * 256;
  float* aw2t = aw1t + 256 * 64;

  hipLaunchKernelGGL(transpose_fm, dim3(64, 4, 8), dim3(64, 4), 0, stream, fm, fm_t);
  hipLaunchKernelGGL(prep_weights, dim3(1), dim3(256), 0, stream,
                     pw1, pb1, g1, bb1, m1, v1, pw2, aw1, ab1, g2, bb2, m2, v2,
                     aw2, w1f, b1f, ab1f, pw2t, aw1t, aw2t);
  hipLaunchKernelGGL(fps_kernel, dim3(8), dim3(1024), 0, stream, verts, fpsi);
  hipLaunchKernelGGL(knn_kernel, dim3(8192), dim3(64), 0, stream, verts, fpsi, knni);
  hipLaunchKernelGGL(fused_kernel, dim3(8192), dim3(256), 0, stream,
                     verts, fm_t, fpsi, knni, w1f, b1f, pw2t, pb2, aw1t, ab1f,
                     aw2t, ab2, out);
}